// Round 15
// baseline (1250.001 us; speedup 1.0000x reference)
//
#include <hip/hip_runtime.h>
#include <hip/hip_bf16.h>

// CustomLMHead: C[M,N] = X[M,K] @ (Wq[N,K] * scale[N])^T
// M=2048, N=151936, K=896.
//
// INT8 path: W exactly int8; X quantized per-row (absmax/127, RNE);
// C = (Xq . Wq8) * Sx[m] * Sw[n], exact int32 accumulation via
// mfma_i32_16x16x64_i8.
//
// THIS ROUND: barrier-free K-sweep. One 512-thread workgroup per
// (n-strip 128 cols x m-half 1024 rows). The ENTIRE W strip (128x896 i8 =
// 114,688 B) is loaded into LDS once (112 gload_lds + one __syncthreads).
// After that: ZERO barriers, ZERO cross-wave dependencies. Each of 8 waves
// owns a 64x64 output block per 256-row supertile (4 supertiles), looping
// K-steps with: A frags global->reg (Xq is 1.8MB, L2-resident; prefetch
// 1 step ahead into alternating reg sets), B frags from read-only LDS
// (proven physoff layout), 16 MFMA, direct scattered stores. All memory
// waits compiler-managed (no inline vmcnt in the loop).
// Fallback (small ws): bf16 reg-staging kernel with in-loop conversion.

#define M_DIM 2048
#define N_DIM 151936
#define K_DIM 896

#define NKT 14                   // 896 / 64
#define NSTRIP (N_DIM / 128)     // 1187 (exact)
#define NWG (NSTRIP * 2)         // 2374 (m-halves); 2374 % 8 == 6

typedef __attribute__((ext_vector_type(8))) short bf16x8;
typedef __attribute__((ext_vector_type(4))) float f32x4;
typedef __attribute__((ext_vector_type(4))) int   i32x4;
typedef __attribute__((ext_vector_type(4))) unsigned int u32x4;
typedef __attribute__((ext_vector_type(2))) unsigned int u32x2;

static __device__ __forceinline__ unsigned short f2bf(float f) {
    unsigned int u = __builtin_bit_cast(unsigned int, f);
    u += 0x7FFFu + ((u >> 16) & 1u);
    return (unsigned short)(u >> 16);
}
static __device__ __forceinline__ unsigned int pack2(float lo, float hi) {
    return (unsigned int)f2bf(lo) | ((unsigned int)f2bf(hi) << 16);
}
static __device__ __forceinline__ void gload_lds16(const void* g, void* l) {
    __builtin_amdgcn_global_load_lds(
        (const __attribute__((address_space(1))) unsigned int*)g,
        (__attribute__((address_space(3))) unsigned int*)l, 16, 0, 0);
}

// ---------------- preconvert kernels (proven rounds 9-14) ----------------

__global__ void quant_x_kernel(const float* __restrict__ X,
                               signed char* __restrict__ Xq,
                               float* __restrict__ Sx) {
    const int row  = blockIdx.x * 4 + (threadIdx.x >> 6);
    const int lane = threadIdx.x & 63;
    const float* xr = X + (size_t)row * K_DIM;
    float v[14];
    float am = 0.f;
    #pragma unroll
    for (int i = 0; i < 14; ++i) {
        v[i] = xr[lane + i * 64];
        am = fmaxf(am, fabsf(v[i]));
    }
    #pragma unroll
    for (int off = 32; off > 0; off >>= 1)
        am = fmaxf(am, __shfl_xor(am, off));
    am = fmaxf(am, 1e-20f);
    const float inv = 127.f / am;
    if (lane == 0) Sx[row] = am / 127.f;
    signed char* qr = Xq + (size_t)row * K_DIM;
    #pragma unroll
    for (int i = 0; i < 14; ++i)
        qr[lane + i * 64] = (signed char)(int)rintf(v[i] * inv);
}

__global__ void cvt_w8_kernel(const int* __restrict__ Wq,
                              signed char* __restrict__ W8) {
    const long n8 = (long)N_DIM * K_DIM / 8;
    for (long i = (long)blockIdx.x * blockDim.x + threadIdx.x; i < n8;
         i += (long)gridDim.x * blockDim.x) {
        i32x4 a = ((const i32x4*)Wq)[2 * i];
        i32x4 b = ((const i32x4*)Wq)[2 * i + 1];
        unsigned int lo = (unsigned int)(a[0] & 0xff) |
                          ((unsigned int)(a[1] & 0xff) << 8) |
                          ((unsigned int)(a[2] & 0xff) << 16) |
                          ((unsigned int)(a[3] & 0xff) << 24);
        unsigned int hi = (unsigned int)(b[0] & 0xff) |
                          ((unsigned int)(b[1] & 0xff) << 8) |
                          ((unsigned int)(b[2] & 0xff) << 16) |
                          ((unsigned int)(b[3] & 0xff) << 24);
        u32x2 o; o[0] = lo; o[1] = hi;
        ((u32x2*)W8)[i] = o;
    }
}

// ---------------- barrier-free W-resident INT8 GEMM ----------------

__global__ __launch_bounds__(512, 1)
void lmhead_gemm_i8(const signed char* __restrict__ Xq,
                    const signed char* __restrict__ W8,
                    const float* __restrict__ Sw,
                    const float* __restrict__ Sx,
                    float* __restrict__ O)
{
    // whole W strip: [k-tile][row 0..127][64 bytes of K] = 114,688 B
    __shared__ signed char Wlds[NKT][128][64];

    const int tid  = threadIdx.x;
    const int lane = tid & 63;
    const int wave = tid >> 6;      // 0..7
    const int mq   = wave >> 1;     // 0..3 (64-row band within supertile)
    const int wc   = wave & 1;      // 0..1 (64-col half of the strip)

    // bijective XCD-chunked swizzle (NWG % 8 = 6, m204 formula);
    // adjacent wg (same nb, both m-halves) land on the same XCD.
    const int bid = blockIdx.x;
    const int xcd = bid & 7, lin = bid >> 3;
    const int q = NWG / 8, r = NWG % 8;   // 296, 6
    const int wg = (xcd < r ? xcd * (q + 1)
                            : r * (q + 1) + (xcd - r) * q) + lin;
    const int nb = wg >> 1;         // 0..1186
    const int mh = wg & 1;          // 0..1

    // ---- W strip -> LDS, ONCE (T2 pre-swizzled source, proven) ----
    // per gload_lds: wave covers 16 rows of 64B; dest row = base+(lane>>2),
    // phys slot = lane&3; source slot = (lane&3)^((lane>>3)&3).
    const int lslot = (lane & 3) ^ ((lane >> 3) & 3);
    const signed char* srcW =
        W8 + (size_t)(nb * 128 + wave * 16 + (lane >> 2)) * K_DIM + lslot * 16;
    #pragma unroll
    for (int kt = 0; kt < NKT; ++kt)
        gload_lds16(srcW + kt * 64, &Wlds[kt][wave * 16][0]);
    asm volatile("s_waitcnt vmcnt(0)" ::: "memory");
    __syncthreads();   // the ONLY block-wide sync in this kernel

    // frag reads: row = wc*64 + nf*16 + (lane&15);
    // phys 16B-octet = (lane>>4) ^ ((lane>>1)&3)  (uniform-8/bank, proven)
    const int physoff = ((lane >> 4) ^ ((lane >> 1) & 3)) * 16;
    const int brow    = wc * 64 + (lane & 15);

    float scn[4];
    #pragma unroll
    for (int nf = 0; nf < 4; ++nf)
        scn[nf] = Sw[nb * 128 + wc * 64 + nf * 16 + (lane & 15)];

    const int li  = lane & 15;
    const int qw4 = (lane >> 4) * 4;

    for (int s = 0; s < 4; ++s) {
        const int mbase = mh * 1024 + s * 256;
        const int mrow0 = mbase + mq * 64;

        // A: global->reg, exact MFMA fragment gather (16 rows x 64B / instr)
        const signed char* aPtr =
            Xq + (size_t)(mrow0 + li) * K_DIM + (lane >> 4) * 16;

        // Sx for my 16 output rows (4 per mf), f32x4-aligned
        f32x4 sxv0 = *(const f32x4*)&Sx[mrow0 +  0 + qw4];
        f32x4 sxv1 = *(const f32x4*)&Sx[mrow0 + 16 + qw4];
        f32x4 sxv2 = *(const f32x4*)&Sx[mrow0 + 32 + qw4];
        f32x4 sxv3 = *(const f32x4*)&Sx[mrow0 + 48 + qw4];

        i32x4 acc[4][4];
        #pragma unroll
        for (int i = 0; i < 4; ++i)
            #pragma unroll
            for (int j = 0; j < 4; ++j)
                acc[i][j] = i32x4{0, 0, 0, 0};

        i32x4 afE[4], afO[4], bfr[4];

#define LOAD_A(DST, T) do { \
    _Pragma("unroll") \
    for (int mf = 0; mf < 4; ++mf) \
        DST[mf] = *(const i32x4*)(aPtr + (size_t)mf * 16 * K_DIM + (T) * 64); \
} while (0)
#define READ_B(T) do { \
    _Pragma("unroll") \
    for (int nf = 0; nf < 4; ++nf) \
        bfr[nf] = *(const i32x4*)&Wlds[T][brow + nf * 16][physoff]; \
} while (0)
#define MFMA16(AF) do { \
    _Pragma("unroll") \
    for (int mf = 0; mf < 4; ++mf) { \
        _Pragma("unroll") \
        for (int nf = 0; nf < 4; ++nf) \
            acc[mf][nf] = __builtin_amdgcn_mfma_i32_16x16x64_i8( \
                AF[mf], bfr[nf], acc[mf][nf], 0, 0, 0); \
    } \
} while (0)

        LOAD_A(afE, 0);
        #pragma unroll
        for (int tt = 0; tt < NKT; tt += 2) {
            // t = tt (even): compute on afE, prefetch afO
            if (tt + 1 < NKT) LOAD_A(afO, tt + 1);
            READ_B(tt);
            MFMA16(afE);
            // t = tt+1 (odd): compute on afO, prefetch afE
            if (tt + 2 < NKT) LOAD_A(afE, tt + 2);
            READ_B(tt + 1);
            MFMA16(afO);
        }

#undef LOAD_A
#undef READ_B
#undef MFMA16

        // direct scattered stores (64B segments; fire-and-forget — they
        // drain under the next supertile's K-loop, no barriers involved)
        #pragma unroll
        for (int mf = 0; mf < 4; ++mf) {
            const f32x4 sxv = (mf == 0) ? sxv0 : (mf == 1) ? sxv1
                            : (mf == 2) ? sxv2 : sxv3;
            #pragma unroll
            for (int nf = 0; nf < 4; ++nf) {
                const float sc = scn[nf];
                const size_t gcol = (size_t)(nb * 128 + wc * 64 + nf * 16 + li);
                #pragma unroll
                for (int rr = 0; rr < 4; ++rr) {
                    const size_t grow = (size_t)(mrow0 + mf * 16 + qw4 + rr);
                    O[grow * N_DIM + gcol] =
                        (float)acc[mf][nf][rr] * sc * sxv[rr];
                }
            }
        }
    }
}

// ---------------- fallback: bf16 reg staging + in-loop convert ----------------

#define FBM 128
#define FBN 128
#define FBK 32
#define FNSTEPS (K_DIM / FBK)
#define FMB (M_DIM / FBM)
#define FNB (N_DIM / FBN)
#define FNWG (FMB * FNB)

__global__ __launch_bounds__(256, 2)
void lmhead_gemm_conv(const float* __restrict__ X,
                      const int* __restrict__ Wq,
                      const float* __restrict__ S,
                      float* __restrict__ O)
{
    __shared__ unsigned short Alds[2][FBM][FBK];
    __shared__ unsigned short Blds2[2][FBN][FBK];

    const int tid  = threadIdx.x;
    const int lane = tid & 63;
    const int wave = tid >> 6;
    const int wr   = wave >> 1;
    const int wc   = wave & 1;

    const int bid = blockIdx.x;
    const int wg  = (bid & 7) * (FNWG / 8) + (bid >> 3);
    const int mb  = wg % FMB;
    const int nb  = wg / FMB;

    const int srow = tid >> 1;
    const int skh  = (tid & 1) * 16;

    const float* aptr = X  + (size_t)(mb * FBM + srow) * K_DIM + skh;
    const int*   wptr = Wq + (size_t)(nb * FBN + srow) * K_DIM + skh;

    f32x4 av[4];
    i32x4 wv[4];

    auto load_tiles = [&](int k0) {
        const f32x4* ap = (const f32x4*)(aptr + k0);
        const i32x4* wp = (const i32x4*)(wptr + k0);
        av[0] = ap[0]; av[1] = ap[1]; av[2] = ap[2]; av[3] = ap[3];
        wv[0] = wp[0]; wv[1] = wp[1]; wv[2] = wp[2]; wv[3] = wp[3];
    };

    auto stage = [&](int buf) {
        unsigned int apk[8], wpk[8];
        #pragma unroll
        for (int i = 0; i < 8; ++i) {
            apk[i] = pack2(av[(2*i) >> 2][(2*i) & 3], av[(2*i+1) >> 2][(2*i+1) & 3]);
            wpk[i] = pack2((float)wv[(2*i) >> 2][(2*i) & 3], (float)wv[(2*i+1) >> 2][(2*i+1) & 3]);
        }
        *(u32x4*)&Alds[buf][srow][skh]      = u32x4{apk[0], apk[1], apk[2], apk[3]};
        *(u32x4*)&Alds[buf][srow][skh + 8]  = u32x4{apk[4], apk[5], apk[6], apk[7]};
        *(u32x4*)&Blds2[buf][srow][skh]     = u32x4{wpk[0], wpk[1], wpk[2], wpk[3]};
        *(u32x4*)&Blds2[buf][srow][skh + 8] = u32x4{wpk[4], wpk[5], wpk[6], wpk[7]};
    };

    f32x4 acc[4][4];
    #pragma unroll
    for (int i = 0; i < 4; ++i)
        #pragma unroll
        for (int j = 0; j < 4; ++j)
            acc[i][j] = f32x4{0.f, 0.f, 0.f, 0.f};

    load_tiles(0);
    stage(0);
    __syncthreads();

    int cur = 0;
    for (int s = 0; s < FNSTEPS; ++s) {
        if (s + 1 < FNSTEPS) load_tiles((s + 1) * FBK);

        bf16x8 af[4], bfr[4];
        const int arow = wr * 64 + (lane & 15);
        const int brow = wc * 64 + (lane & 15);
        const int kb   = (lane >> 4) * 8;
        #pragma unroll
        for (int mf = 0; mf < 4; ++mf)
            af[mf] = *(const bf16x8*)&Alds[cur][arow + mf * 16][kb];
        #pragma unroll
        for (int nf = 0; nf < 4; ++nf)
            bfr[nf] = *(const bf16x8*)&Blds2[cur][brow + nf * 16][kb];

        #pragma unroll
        for (int mf = 0; mf < 4; ++mf)
            #pragma unroll
            for (int nf = 0; nf < 4; ++nf)
                acc[mf][nf] = __builtin_amdgcn_mfma_f32_16x16x32_bf16(
                    af[mf], bfr[nf], acc[mf][nf], 0, 0, 0);

        if (s + 1 < FNSTEPS) stage(cur ^ 1);
        __syncthreads();
        cur ^= 1;
    }

    #pragma unroll
    for (int nf = 0; nf < 4; ++nf) {
        const int n = nb * FBN + wc * 64 + nf * 16 + (lane & 15);
        const float sc = S[n];
        #pragma unroll
        for (int mf = 0; mf < 4; ++mf) {
            const int m0 = mb * FBM + wr * 64 + mf * 16 + ((lane >> 4) << 2);
            #pragma unroll
            for (int r = 0; r < 4; ++r)
                O[(size_t)(m0 + r) * N_DIM + n] = acc[mf][nf][r] * sc;
        }
    }
}

// ---------------- launch ----------------

extern "C" void kernel_launch(void* const* d_in, const int* in_sizes, int n_in,
                              void* d_out, int out_size, void* d_ws, size_t ws_size,
                              hipStream_t stream) {
    const float* X  = (const float*)d_in[0];
    const int*   Wq = (const int*)d_in[1];
    const float* S  = (const float*)d_in[2];
    float*       O  = (float*)d_out;

    const size_t XQ_BYTES = (size_t)M_DIM * K_DIM;            // 1,835,008
    const size_t SX_BYTES = (size_t)M_DIM * sizeof(float);    // 8,192
    const size_t W8_BYTES = (size_t)N_DIM * K_DIM;            // 136,134,656

    if (ws_size >= XQ_BYTES + SX_BYTES + W8_BYTES) {
        signed char* xq = (signed char*)d_ws;
        float*       sx = (float*)((char*)d_ws + XQ_BYTES);
        signed char* w8 = (signed char*)((char*)d_ws + XQ_BYTES + SX_BYTES);
        quant_x_kernel<<<M_DIM / 4, 256, 0, stream>>>(X, xq, sx);
        cvt_w8_kernel<<<2048, 256, 0, stream>>>(Wq, w8);
        lmhead_gemm_i8<<<NWG, 512, 0, stream>>>(xq, w8, S, sx, O);
    } else {
        lmhead_gemm_conv<<<FNWG, 256, 0, stream>>>(X, Wq, S, O);
    }
}